// Round 4
// baseline (729.157 us; speedup 1.0000x reference)
//
#include <hip/hip_runtime.h>
#include <hip/hip_cooperative_groups.h>

namespace cg = cooperative_groups;

#define NPTS 512
#define DIM  256
#define HID  128
#define NSEG 64
#define LN_EPS 1e-5f

typedef short s16x4 __attribute__((ext_vector_type(4)));
typedef short s16x8 __attribute__((ext_vector_type(8)));
typedef float f32x4 __attribute__((ext_vector_type(4)));
typedef const float* fpc;

__device__ __forceinline__ unsigned short f2bf(float f) {
  unsigned int u = __builtin_bit_cast(unsigned int, f);
  u += 0x7FFFu + ((u >> 16) & 1u);
  return (unsigned short)(u >> 16);
}

struct MegaP {
  fpc coords; fpc features; const int* labels;
  fpc ge_w1; fpc ge_b1; fpc ge_g1; fpc ge_be1;
  fpc ge_w2; fpc ge_b2; fpc ge_g2; fpc ge_be2;
  fpc ag_w1; fpc ag_b1; fpc ag_g1; fpc ag_be1;
  fpc ag_w2; fpc ag_b2; fpc ag_g2; fpc ag_be2;
  fpc wq; fpc bq; fpc wk; fpc bk; fpc wv; fpc bv; fpc wo; fpc bo;
  float* geo_ctx; float* comb; float* cntf; float* enh;
  float* Q; float* K; float* V; float* O; float* out;
  unsigned short* gmw; float* uw; float* tvw; float* scw; float* qfw;
};

// LDS union across stages (max ~32.3KB -> 4 blocks/CU, grid 1024 co-resident)
union SMem {
  struct {
    float xs[NPTS][8];
    float st[NPTS][2];
    float qf[128];
    unsigned short h1s[32][136];
    float red2[32][12];
    float haS[128];
    float srsS, srmS;
  } s1;
  struct { int labS[NPTS]; float mfS[DIM]; float h1S[HID]; float red[8]; } s2;
  struct { float Xs[8][256]; } s4;
  struct { float Sx[16][516]; float rinv[16]; } s5;
  struct { float Xs[4][256]; } s6;
};

// ---------------- v7: single cooperative mega-kernel --------------------------------------
// v6 lesson: k1 127.6us but total stuck at 410 — per-dispatch gap ~30-45us x 6 launches is
// the dominant cost (rest-of-graph stable ~230-280us vs ~45us analytic; adding the tiny k0
// launch ADDED ~30us). v7 fuses all stages into one persistent cooperative kernel with
// grid.sync() between stages. Stage bodies identical to v6 kernels (absmax must not move).
__global__ __launch_bounds__(256, 4) void mega(MegaP p)
{
  __shared__ __align__(16) SMem sm;
  cg::grid_group grid = cg::this_grid();
  const int t = threadIdx.x;
  const int lane = t & 63;
  const int wid = t >> 6;

  // ===== stage P: k0 prep (130 items) =====================================================
  for (int blk = blockIdx.x; blk < 130; blk += gridDim.x) {
    if (t < 128) {
      if (blk < 128) {
        const int c = blk;
        float acc = 0.f;
        for (int d = 0; d < DIM; ++d) acc += p.ge_w2[d * HID + c] * p.ge_w2[d * HID + t];
        p.gmw[c * HID + t] = f2bf(acc);
      } else if (blk == 128) {
        float uu = 0.f, tv = 0.f;
        for (int d = 0; d < DIM; ++d) { const float w = p.ge_w2[d * HID + t]; uu += w; tv += p.ge_b2[d] * w; }
        p.uw[t] = uu; p.tvw[t] = tv;
        if (t == 0) {
          float s = 0.f, s2 = 0.f;
          for (int d = 0; d < DIM; ++d) { const float bb = p.ge_b2[d]; s += bb; s2 += bb * bb; }
          p.scw[0] = s; p.scw[1] = s2;
        }
      } else {
        if (t < 101) {
          float acc = 0.f;
          if (t < 81) {
            const int a = t / 9, c = t % 9;
            for (int h = 0; h < HID; ++h) acc += p.ge_w1[h * 9 + a] * p.ge_w1[h * 9 + c];
            p.qfw[a * 12 + c] = acc;
          } else if (t < 90) {
            const int a = t - 81;
            for (int h = 0; h < HID; ++h) acc += p.ge_w1[h * 9 + a];
            p.qfw[108 + a] = acc;
          } else if (t < 99) {
            const int a = t - 90;
            for (int h = 0; h < HID; ++h) acc += p.ge_b1[h] * p.ge_w1[h * 9 + a];
            p.qfw[117 + a] = acc;
          } else if (t == 99) {
            float acc2 = 0.f;
            for (int h = 0; h < HID; ++h) acc2 += p.ge_b1[h];
            p.qfw[126] = acc2;
          } else {
            float acc2 = 0.f;
            for (int h = 0; h < HID; ++h) acc2 += p.ge_b1[h] * p.ge_b1[h];
            p.qfw[127] = acc2;
          }
        }
      }
    }
  }
  grid.sync();

  // ===== stage 1: k1 geo (1024 items) =====================================================
  for (int bi = blockIdx.x; bi < 1024; bi += gridDim.x) {
    const int b = bi >> 9;
    if (t < 128) sm.s1.qf[t] = p.qfw[t];

    float w1r[2][7], b1r[2], g1r[2], be1r[2];
    #pragma unroll
    for (int r = 0; r < 2; ++r) {
      const int hh = lane * 2 + r;
      w1r[r][0] = p.ge_w1[hh * 9 + 0]; w1r[r][1] = p.ge_w1[hh * 9 + 1];
      w1r[r][2] = p.ge_w1[hh * 9 + 2]; w1r[r][3] = p.ge_w1[hh * 9 + 3];
      w1r[r][4] = p.ge_w1[hh * 9 + 6]; w1r[r][5] = p.ge_w1[hh * 9 + 7];
      w1r[r][6] = p.ge_w1[hh * 9 + 8];
      b1r[r] = p.ge_b1[hh]; g1r[r] = p.ge_g1[hh]; be1r[r] = p.ge_be1[hh];
    }
    const int n16 = lane & 15;
    const int q16 = lane >> 4;
    const int colc0 = wid * 32 + n16;
    s16x8 gfrag[2][4];
    float u_c[2], tv_c[2];
    #pragma unroll
    for (int dt = 0; dt < 2; ++dt) {
      const int c = colc0 + dt * 16;
      u_c[dt] = p.uw[c];
      tv_c[dt] = 2.f * p.tvw[c];
      #pragma unroll
      for (int kt = 0; kt < 4; ++kt)
        gfrag[dt][kt] = *(const s16x8*)&p.gmw[c * HID + kt * 32 + q16 * 8];
    }
    const float sb = p.scw[0], sb2 = p.scw[1];
    const float cix = p.coords[bi * 3 + 0];
    const float ciy = p.coords[bi * 3 + 1];
    const float ciz = p.coords[bi * 3 + 2];
    __syncthreads();

    #pragma unroll
    for (int jj = 0; jj < 2; ++jj) {
      const int j = t + jj * 256;
      const float cjx = p.coords[(b * NPTS + j) * 3 + 0];
      const float cjy = p.coords[(b * NPTS + j) * 3 + 1];
      const float cjz = p.coords[(b * NPTS + j) * 3 + 2];
      const float rx = cix - cjx, ry = ciy - cjy, rz = ciz - cjz;
      const float dist = sqrtf(rx * rx + ry * ry + rz * rz);
      const float inv = 1.f / fmaxf(dist, 1e-12f);
      const float r0 = rx * inv, r1 = ry * inv, r2 = rz * inv;
      const float x0 = dist, x1 = r0, x2 = r1, x3 = r2;
      const float x6 = r1 * r2, x7 = r0 * r1, x8 = r0 * r2;
      float S1 = sm.s1.qf[126] + sm.s1.qf[108] * x0 + sm.s1.qf[109] * x1 + sm.s1.qf[110] * x2
               + sm.s1.qf[111] * x3 + sm.s1.qf[114] * x6 + sm.s1.qf[115] * x7 + sm.s1.qf[116] * x8;
      float tx = sm.s1.qf[117] * x0 + sm.s1.qf[118] * x1 + sm.s1.qf[119] * x2 + sm.s1.qf[120] * x3
               + sm.s1.qf[123] * x6 + sm.s1.qf[124] * x7 + sm.s1.qf[125] * x8;
      const float xv[9] = {x0, x1, x2, x3, 0.f, 0.f, x6, x7, x8};
      float quad = 0.f;
      #pragma unroll
      for (int a = 0; a < 9; ++a) {
        if (a == 4 || a == 5) continue;
        const f32x4 q0 = *(const f32x4*)&sm.s1.qf[a * 12];
        const f32x4 q1 = *(const f32x4*)&sm.s1.qf[a * 12 + 4];
        const f32x4 q2 = *(const f32x4*)&sm.s1.qf[a * 12 + 8];
        const float ya = q0[0] * x0 + q0[1] * x1 + q0[2] * x2 + q0[3] * x3
                       + q1[2] * x6 + q1[3] * x7 + q2[0] * x8;
        quad += ya * xv[a];
      }
      const float S2 = quad + 2.f * tx + sm.s1.qf[127];
      const float mean = S1 * (1.f / 128.f);
      const float var = fmaxf(S2 * (1.f / 128.f) - mean * mean, 0.f);
      sm.s1.st[j][0] = mean;
      sm.s1.st[j][1] = rsqrtf(var + LN_EPS);
      f32x4 X0; X0[0] = x0; X0[1] = x1; X0[2] = x2; X0[3] = x3;
      f32x4 X1; X1[0] = x6; X1[1] = x7; X1[2] = x8; X1[3] = 0.f;
      *(f32x4*)&sm.s1.xs[j][0] = X0;
      *(f32x4*)&sm.s1.xs[j][4] = X1;
    }
    __syncthreads();

    float haL[2] = {0.f, 0.f};
    float srs = 0.f, srm = 0.f;
    const bool own = (wid == 0) && (n16 == 0);

    for (int jb = 0; jb < NPTS; jb += 32) {
      #pragma unroll
      for (int sr = 0; sr < 8; ++sr) {
        const int m = sr * 4 + wid;
        const int j = jb + m;
        const f32x4 X0 = *(const f32x4*)&sm.s1.xs[j][0];
        const f32x4 X1 = *(const f32x4*)&sm.s1.xs[j][4];
        const float2 ms = *(const float2*)&sm.s1.st[j][0];
        unsigned int pk = 0;
        #pragma unroll
        for (int r = 0; r < 2; ++r) {
          const float a = b1r[r]
            + X0[0] * w1r[r][0] + X0[1] * w1r[r][1] + X0[2] * w1r[r][2] + X0[3] * w1r[r][3]
            + X1[0] * w1r[r][4] + X1[1] * w1r[r][5] + X1[2] * w1r[r][6];
          const float e = (a - ms.x) * ms.y * g1r[r] + be1r[r];
          pk |= ((unsigned int)f2bf(fmaxf(e, 0.f))) << (16 * r);
        }
        *(unsigned int*)&sm.s1.h1s[m][lane * 2] = pk;
      }
      __syncthreads();
      f32x4 acc2[2][2];
      #pragma unroll
      for (int mt = 0; mt < 2; ++mt)
        #pragma unroll
        for (int dt = 0; dt < 2; ++dt) {
          f32x4 z; z[0] = tv_c[dt]; z[1] = tv_c[dt]; z[2] = tv_c[dt]; z[3] = tv_c[dt];
          acc2[mt][dt] = z;
        }
      #pragma unroll
      for (int mt = 0; mt < 2; ++mt)
        #pragma unroll
        for (int kt = 0; kt < 4; ++kt) {
          const s16x8 af = *(const s16x8*)&sm.s1.h1s[mt * 16 + n16][kt * 32 + q16 * 8];
          #pragma unroll
          for (int dt = 0; dt < 2; ++dt)
            acc2[mt][dt] = __builtin_amdgcn_mfma_f32_16x16x32_bf16(af, gfrag[dt][kt], acc2[mt][dt], 0, 0, 0);
        }
      float h1v[2][2][4];
      #pragma unroll
      for (int mt = 0; mt < 2; ++mt)
        #pragma unroll
        for (int dt = 0; dt < 2; ++dt)
          #pragma unroll
          for (int r = 0; r < 4; ++r) {
            const unsigned short hv = sm.s1.h1s[mt * 16 + q16 * 4 + r][colc0 + dt * 16];
            h1v[mt][dt][r] = __builtin_bit_cast(float, ((unsigned int)hv) << 16);
          }
      #pragma unroll
      for (int mt = 0; mt < 2; ++mt) {
        float sR[4], qR[4];
        #pragma unroll
        for (int r = 0; r < 4; ++r) {
          sR[r] = u_c[0] * h1v[mt][0][r] + u_c[1] * h1v[mt][1][r];
          qR[r] = acc2[mt][0][r] * h1v[mt][0][r] + acc2[mt][1][r] * h1v[mt][1][r];
        }
        #pragma unroll
        for (int off = 1; off < 16; off <<= 1)
          #pragma unroll
          for (int r = 0; r < 4; ++r) {
            sR[r] += __shfl_xor(sR[r], off);
            qR[r] += __shfl_xor(qR[r], off);
          }
        if (n16 == 0)
          #pragma unroll
          for (int r = 0; r < 4; ++r) {
            sm.s1.red2[mt * 16 + q16 * 4 + r][wid * 2 + 0] = sR[r];
            sm.s1.red2[mt * 16 + q16 * 4 + r][wid * 2 + 1] = qR[r];
          }
      }
      __syncthreads();
      #pragma unroll
      for (int mt = 0; mt < 2; ++mt)
        #pragma unroll
        for (int r = 0; r < 4; ++r) {
          const int row = mt * 16 + q16 * 4 + r;
          const f32x4 p0 = *(const f32x4*)&sm.s1.red2[row][0];
          const f32x4 p1 = *(const f32x4*)&sm.s1.red2[row][4];
          const float s = p0[0] + p0[2] + p1[0] + p1[2];
          const float q = p0[1] + p0[3] + p1[1] + p1[3];
          const float mean = (s + sb) * (1.f / 256.f);
          const float var = fmaxf((q + sb2) * (1.f / 256.f) - mean * mean, 0.f);
          const float rs = rsqrtf(var + LN_EPS);
          haL[0] += rs * h1v[mt][0][r];
          haL[1] += rs * h1v[mt][1][r];
          if (own) { srs += rs; srm += rs * mean; }
        }
    }

    haL[0] += __shfl_xor(haL[0], 16); haL[0] += __shfl_xor(haL[0], 32);
    haL[1] += __shfl_xor(haL[1], 16); haL[1] += __shfl_xor(haL[1], 32);
    float sa = srs, smv = srm;
    sa += __shfl_xor(sa, 16); sa += __shfl_xor(sa, 32);
    smv += __shfl_xor(smv, 16); smv += __shfl_xor(smv, 32);
    if (t == 0) { sm.s1.srsS = sa; sm.s1.srmS = smv; }
    if (lane < 16) { sm.s1.haS[colc0] = haL[0]; sm.s1.haS[colc0 + 16] = haL[1]; }
    __syncthreads();
    const float srsT = sm.s1.srsS, srmT = sm.s1.srmS;
    float dot = 0.f;
    for (int k = 0; k < HID; k += 4) {
      const f32x4 w = *(const f32x4*)&p.ge_w2[t * HID + k];
      const f32x4 h = *(const f32x4*)&sm.s1.haS[k];
      dot += w[0] * h[0] + w[1] * h[1] + w[2] * h[2] + w[3] * h[3];
    }
    p.geo_ctx[bi * DIM + t] = (dot + p.ge_b2[t] * srsT - srmT) * (1.f / 512.f) * p.ge_g2[t] + p.ge_be2[t];
    __syncthreads();   // protect sm reuse if this block loops again
  }
  grid.sync();

  // ===== stage 2: k2 agg (128 items) ======================================================
  for (int item = blockIdx.x; item < 128; item += gridDim.x) {
    const int b = item >> 6;
    const int s = item & 63;
    for (int n = t; n < NPTS; n += 256) sm.s2.labS[n] = p.labels[b * NPTS + n];
    __syncthreads();
    float accf = 0.f, accgv = 0.f;
    int cnt = 0;
    for (int n = 0; n < NPTS; n += 4) {
      const int4 l4 = *(const int4*)&sm.s2.labS[n];
      if (l4.x == s) { cnt++; accf += p.features[(b * NPTS + n + 0) * DIM + t]; accgv += p.geo_ctx[(b * NPTS + n + 0) * DIM + t]; }
      if (l4.y == s) { cnt++; accf += p.features[(b * NPTS + n + 1) * DIM + t]; accgv += p.geo_ctx[(b * NPTS + n + 1) * DIM + t]; }
      if (l4.z == s) { cnt++; accf += p.features[(b * NPTS + n + 2) * DIM + t]; accgv += p.geo_ctx[(b * NPTS + n + 2) * DIM + t]; }
      if (l4.w == s) { cnt++; accf += p.features[(b * NPTS + n + 3) * DIM + t]; accgv += p.geo_ctx[(b * NPTS + n + 3) * DIM + t]; }
    }
    const float denom = fmaxf((float)cnt, 1.f);
    const float mfd = accf / denom, mgd = accgv / denom;
    sm.s2.mfS[t] = mfd;
    __syncthreads();
    float hval = 0.f;
    if (t < HID) {
      float o = p.ag_b1[t];
      for (int k = 0; k < DIM; k += 4) {
        const f32x4 x = *(const f32x4*)&sm.s2.mfS[k];
        const f32x4 w = *(const f32x4*)&p.ag_w1[t * DIM + k];
        o += x[0] * w[0] + x[1] * w[1] + x[2] * w[2] + x[3] * w[3];
      }
      hval = o;
    }
    float sv = (t < HID) ? hval : 0.f;
    float qv = (t < HID) ? hval * hval : 0.f;
    #pragma unroll
    for (int off = 1; off < 64; off <<= 1) { sv += __shfl_xor(sv, off); qv += __shfl_xor(qv, off); }
    if (lane == 0 && wid < 2) { sm.s2.red[wid * 2] = sv; sm.s2.red[wid * 2 + 1] = qv; }
    __syncthreads();
    if (t < HID) {
      const float s1 = sm.s2.red[0] + sm.s2.red[2], q1 = sm.s2.red[1] + sm.s2.red[3];
      const float mean = s1 * (1.f / 128.f);
      const float var = fmaxf(q1 * (1.f / 128.f) - mean * mean, 0.f);
      const float rs = rsqrtf(var + LN_EPS);
      sm.s2.h1S[t] = fmaxf((hval - mean) * rs * p.ag_g1[t] + p.ag_be1[t], 0.f);
    }
    __syncthreads();
    float o = p.ag_b2[t];
    for (int k = 0; k < HID; k += 4) {
      const f32x4 x = *(const f32x4*)&sm.s2.h1S[k];
      const f32x4 w = *(const f32x4*)&p.ag_w2[t * HID + k];
      o += x[0] * w[0] + x[1] * w[1] + x[2] * w[2] + x[3] * w[3];
    }
    float sv2 = o, qv2 = o * o;
    #pragma unroll
    for (int off = 1; off < 64; off <<= 1) { sv2 += __shfl_xor(sv2, off); qv2 += __shfl_xor(qv2, off); }
    if (lane == 0) { sm.s2.red[wid * 2] = sv2; sm.s2.red[wid * 2 + 1] = qv2; }
    __syncthreads();
    const float sa = sm.s2.red[0] + sm.s2.red[2] + sm.s2.red[4] + sm.s2.red[6];
    const float qa = sm.s2.red[1] + sm.s2.red[3] + sm.s2.red[5] + sm.s2.red[7];
    const float mean = sa * (1.f / 256.f);
    const float var = fmaxf(qa * (1.f / 256.f) - mean * mean, 0.f);
    const float rs = rsqrtf(var + LN_EPS);
    const float e = (o - mean) * rs * p.ag_g2[t] + p.ag_be2[t];
    p.comb[(b * NSEG + s) * DIM + t] = e + mgd;
    if (t == 0) p.cntf[b * NSEG + s] = (float)cnt;
    __syncthreads();
  }
  grid.sync();

  // ===== stage 3: k4 qkv (384 items) ======================================================
  for (int item = blockIdx.x; item < 384; item += gridDim.x) {
    const int proj = item >> 7;
    const int rem = item & 127;
    const int b = rem >> 6;
    const int nt = rem & 63;
    const int n0 = b * NPTS + nt * 8;
    fpc W = (proj == 0) ? p.wq : (proj == 1 ? p.wk : p.wv);
    fpc bias = (proj == 0) ? p.bq : (proj == 1 ? p.bk : p.bv);
    float* out = (proj == 0) ? p.Q : (proj == 1 ? p.K : p.V);
    for (int idx = t * 4; idx < 8 * 256; idx += 1024) {
      const int r = idx >> 8, c = idx & 255;
      const int row = n0 + r;
      f32x4 v;
      if (proj == 0) {
        const int l = p.labels[row];
        const float cn = p.cntf[b * NSEG + l];
        const f32x4 f = *(const f32x4*)&p.features[row * DIM + c];
        if (cn >= 2.f) {
          const f32x4 cb = *(const f32x4*)&p.comb[(b * NSEG + l) * DIM + c];
          #pragma unroll
          for (int i = 0; i < 4; ++i) v[i] = 0.7f * f[i] + 0.3f * cb[i];
        } else {
          v = f;
        }
        *(f32x4*)&p.enh[row * DIM + c] = v;
      } else {
        v = *(const f32x4*)&p.geo_ctx[row * DIM + c];
      }
      *(f32x4*)&sm.s4.Xs[r][c] = v;
    }
    __syncthreads();
    const int r0 = (t >> 6) * 2;
    const int c0 = (t & 63) * 4;
    float acc[2][4] = {};
    for (int k = 0; k < DIM; k += 4) {
      f32x4 xq[2];
      xq[0] = *(const f32x4*)&sm.s4.Xs[r0][k];
      xq[1] = *(const f32x4*)&sm.s4.Xs[r0 + 1][k];
      f32x4 wf[4];
      #pragma unroll
      for (int c = 0; c < 4; ++c) wf[c] = *(const f32x4*)&W[(c0 + c) * DIM + k];
      #pragma unroll
      for (int r = 0; r < 2; ++r)
        #pragma unroll
        for (int c = 0; c < 4; ++c)
          acc[r][c] += xq[r][0] * wf[c][0] + xq[r][1] * wf[c][1]
                     + xq[r][2] * wf[c][2] + xq[r][3] * wf[c][3];
    }
    #pragma unroll
    for (int r = 0; r < 2; ++r) {
      f32x4 o;
      #pragma unroll
      for (int c = 0; c < 4; ++c) o[c] = acc[r][c] + bias[c0 + c];
      *(f32x4*)&out[(n0 + r0 + r) * DIM + c0] = o;
    }
    __syncthreads();
  }
  grid.sync();

  // ===== stage 4: k5 attention (512 items) ================================================
  for (int item = blockIdx.x; item < 512; item += gridDim.x) {
    const int qt = item & 31;
    const int h = (item >> 5) & 7;
    const int b = item >> 8;
    {
      const int r = t & 15, kc = t >> 4;
      const int qrow = b * NPTS + qt * 16 + r;
      f32x4 qv[8];
      #pragma unroll
      for (int i = 0; i < 8; ++i) qv[i] = *(const f32x4*)&p.Q[qrow * DIM + h * 32 + i * 4];
      for (int kk = 0; kk < 32; ++kk) {
        const int krow = b * NPTS + kc * 32 + kk;
        const f32x4* kp = (const f32x4*)&p.K[krow * DIM + h * 32];
        float sd = 0.f;
        #pragma unroll
        for (int i = 0; i < 8; ++i) {
          const f32x4 kvv = kp[i];
          sd += qv[i][0] * kvv[0] + qv[i][1] * kvv[1] + qv[i][2] * kvv[2] + qv[i][3] * kvv[3];
        }
        sm.s5.Sx[r][kc * 32 + kk] = sd * 0.1767766952966369f;
      }
    }
    __syncthreads();
    {
      const int r2 = t >> 4, cl = t & 15;
      float mx = -3.4e38f;
      for (int i = 0; i < 32; ++i) mx = fmaxf(mx, sm.s5.Sx[r2][cl + 16 * i]);
      #pragma unroll
      for (int off = 1; off < 16; off <<= 1) mx = fmaxf(mx, __shfl_xor(mx, off));
      float smv = 0.f;
      for (int i = 0; i < 32; ++i) {
        const float e = __expf(sm.s5.Sx[r2][cl + 16 * i] - mx);
        sm.s5.Sx[r2][cl + 16 * i] = e;
        smv += e;
      }
      #pragma unroll
      for (int off = 1; off < 16; off <<= 1) smv += __shfl_xor(smv, off);
      if (cl == 0) sm.s5.rinv[r2] = 1.f / smv;
    }
    __syncthreads();
    {
      const int r3 = t >> 4;
      const int e0 = (t & 15) * 2;
      float o0 = 0.f, o1 = 0.f;
      for (int k = 0; k < NPTS; ++k) {
        const float pv = sm.s5.Sx[r3][k];
        const float2 vv = *(const float2*)&p.V[(b * NPTS + k) * DIM + h * 32 + e0];
        o0 += pv * vv.x; o1 += pv * vv.y;
      }
      const float ri = sm.s5.rinv[r3];
      float2 ov; ov.x = o0 * ri; ov.y = o1 * ri;
      *(float2*)&p.O[(b * NPTS + qt * 16 + r3) * DIM + h * 32 + e0] = ov;
    }
    __syncthreads();
  }
  grid.sync();

  // ===== stage 5: k6 out (256 items) ======================================================
  for (int item = blockIdx.x; item < 256; item += gridDim.x) {
    const int b = item >> 7;
    const int nt = item & 127;
    const int n0 = b * NPTS + nt * 4;
    {
      const int idx = t * 4;
      const int r = idx >> 8, c = idx & 255;
      *(f32x4*)&sm.s6.Xs[r][c] = *(const f32x4*)&p.O[(n0 + r) * DIM + c];
    }
    __syncthreads();
    const int r0 = t >> 6;
    const int c0 = (t & 63) * 4;
    float acc[4] = {};
    for (int k = 0; k < DIM; k += 4) {
      const f32x4 xq = *(const f32x4*)&sm.s6.Xs[r0][k];
      #pragma unroll
      for (int c = 0; c < 4; ++c) {
        const f32x4 w = *(const f32x4*)&p.wo[(c0 + c) * DIM + k];
        acc[c] += xq[0] * w[0] + xq[1] * w[1] + xq[2] * w[2] + xq[3] * w[3];
      }
    }
    {
      const int row = n0 + r0;
      const f32x4 ev = *(const f32x4*)&p.enh[row * DIM + c0];
      f32x4 o;
      #pragma unroll
      for (int c = 0; c < 4; ++c)
        o[c] = ev[c] + 0.5f * (acc[c] + p.bo[c0 + c]);
      *(f32x4*)&p.out[row * DIM + c0] = o;
    }
    __syncthreads();
  }
}

extern "C" void kernel_launch(void* const* d_in, const int* in_sizes, int n_in,
                              void* d_out, int out_size, void* d_ws, size_t ws_size,
                              hipStream_t stream)
{
  MegaP p;
  p.coords  = (fpc)d_in[0];
  p.features= (fpc)d_in[1];
  p.labels  = (const int*)d_in[2];
  p.ge_w1 = (fpc)d_in[3];  p.ge_b1 = (fpc)d_in[4];  p.ge_g1 = (fpc)d_in[5];  p.ge_be1 = (fpc)d_in[6];
  p.ge_w2 = (fpc)d_in[7];  p.ge_b2 = (fpc)d_in[8];  p.ge_g2 = (fpc)d_in[9];  p.ge_be2 = (fpc)d_in[10];
  p.ag_w1 = (fpc)d_in[11]; p.ag_b1 = (fpc)d_in[12]; p.ag_g1 = (fpc)d_in[13]; p.ag_be1 = (fpc)d_in[14];
  p.ag_w2 = (fpc)d_in[15]; p.ag_b2 = (fpc)d_in[16]; p.ag_g2 = (fpc)d_in[17]; p.ag_be2 = (fpc)d_in[18];
  p.wq = (fpc)d_in[19]; p.bq = (fpc)d_in[20];
  p.wk = (fpc)d_in[21]; p.bk = (fpc)d_in[22];
  p.wv = (fpc)d_in[23]; p.bv = (fpc)d_in[24];
  p.wo = (fpc)d_in[25]; p.bo = (fpc)d_in[26];

  float* ws = (float*)d_ws;
  p.geo_ctx = ws;                         // 262144
  p.comb    = p.geo_ctx + 262144;         // 32768
  p.cntf    = p.comb + 32768;             // 128
  p.enh     = p.cntf + 128;               // 262144
  p.Q       = p.enh + 262144;             // 262144
  p.K       = p.Q + 262144;               // 262144
  p.V       = p.K + 262144;               // 262144
  p.O       = p.V + 262144;               // 262144
  float* gmwF = p.O + 262144;             // 8192 floats (128x128 bf16)
  p.gmw = (unsigned short*)gmwF;
  p.uw  = gmwF + 8192;                    // 128
  p.tvw = p.uw + 128;                     // 128
  p.scw = p.tvw + 128;                    // 8
  p.qfw = p.scw + 8;                      // 128
  p.out = (float*)d_out;

  int nb = 0;
  hipError_t e = hipOccupancyMaxActiveBlocksPerMultiprocessor(
      &nb, reinterpret_cast<const void*>(mega), 256, 0);
  if (e != hipSuccess || nb < 1) nb = 1;
  int grid = nb * 256;                    // 256 CUs on MI355X
  if (grid > 1024) grid = 1024;

  void* kargs[] = { (void*)&p };
  hipLaunchCooperativeKernel(reinterpret_cast<const void*>(mega),
                             dim3(grid), dim3(256), kargs, 0, stream);
}

// Round 5
// 465.995 us; speedup vs baseline: 1.5647x; 1.5647x over previous
//
#include <hip/hip_runtime.h>

#define NPTS 512
#define DIM  256
#define HID  128
#define NSEG 64
#define LN_EPS 1e-5f

typedef short s16x4 __attribute__((ext_vector_type(4)));
typedef short s16x8 __attribute__((ext_vector_type(8)));
typedef float f32x4 __attribute__((ext_vector_type(4)));
typedef const float* fpc;

__device__ __forceinline__ unsigned short f2bf(float f) {
  unsigned int u = __builtin_bit_cast(unsigned int, f);
  u += 0x7FFFu + ((u >> 16) & 1u);
  return (unsigned short)(u >> 16);
}

// ---------------- K02: k0 prep  +  k2 aggregator (mg-free)  +  mgsum zero ----------------
// v7 lesson: grid.sync costs ~100us each on 8-XCD MI355X (L2 flush, 95MB HBM traffic) —
// fuse only where NO grid-wide dependency exists. k2's MLP input is the FEATURES segment
// mean only; geo enters comb additively -> k2-minus-mg depends only on inputs and fuses
// with k0 prep. mg is accumulated later by k1 via atomics into mgsum (zeroed here).
__global__ void k02_prep_agg(
    fpc ge_w1, fpc ge_b1, fpc ge_w2, fpc ge_b2,
    fpc features, const int* __restrict__ labels,
    fpc ag_w1, fpc ag_b1, fpc ag_g1, fpc ag_be1,
    fpc ag_w2, fpc ag_b2, fpc ag_g2, fpc ag_be2,
    unsigned short* __restrict__ gmw, float* __restrict__ uw,
    float* __restrict__ tvw, float* __restrict__ scw, float* __restrict__ qfw,
    float* __restrict__ comb, float* __restrict__ cntf, float* __restrict__ mgsum)
{
  const int blk = blockIdx.x;
  const int t = threadIdx.x;
  if (blk < 130) {                       // ---- prep (t<128 active)
    if (t < 128) {
      if (blk < 128) {
        const int c = blk;
        float acc = 0.f;
        for (int d = 0; d < DIM; ++d) acc += ge_w2[d * HID + c] * ge_w2[d * HID + t];
        gmw[c * HID + t] = f2bf(acc);
      } else if (blk == 128) {
        float uu = 0.f, tv = 0.f;
        for (int d = 0; d < DIM; ++d) { const float w = ge_w2[d * HID + t]; uu += w; tv += ge_b2[d] * w; }
        uw[t] = uu; tvw[t] = tv;
        if (t == 0) {
          float s = 0.f, s2 = 0.f;
          for (int d = 0; d < DIM; ++d) { const float bb = ge_b2[d]; s += bb; s2 += bb * bb; }
          scw[0] = s; scw[1] = s2;
        }
      } else {
        if (t < 101) {
          float acc = 0.f;
          if (t < 81) {
            const int a = t / 9, c = t % 9;
            for (int h = 0; h < HID; ++h) acc += ge_w1[h * 9 + a] * ge_w1[h * 9 + c];
            qfw[a * 12 + c] = acc;
          } else if (t < 90) {
            const int a = t - 81;
            for (int h = 0; h < HID; ++h) acc += ge_w1[h * 9 + a];
            qfw[108 + a] = acc;
          } else if (t < 99) {
            const int a = t - 90;
            for (int h = 0; h < HID; ++h) acc += ge_b1[h] * ge_w1[h * 9 + a];
            qfw[117 + a] = acc;
          } else if (t == 99) {
            float acc2 = 0.f;
            for (int h = 0; h < HID; ++h) acc2 += ge_b1[h];
            qfw[126] = acc2;
          } else {
            float acc2 = 0.f;
            for (int h = 0; h < HID; ++h) acc2 += ge_b1[h] * ge_b1[h];
            qfw[127] = acc2;
          }
        }
      }
    }
    return;
  }
  // ---- k2 body without geo: comb[b,s] = aggregator_MLP(mean features), cntf, zero mgsum
  const int item = blk - 130;
  const int lane = t & 63;
  const int wid = t >> 6;
  const int b = item >> 6;
  const int s = item & 63;
  __shared__ __align__(16) int labS[NPTS];
  __shared__ __align__(16) float mfS[DIM];
  __shared__ __align__(16) float h1S[HID];
  __shared__ __align__(16) float red[8];
  mgsum[(b * NSEG + s) * DIM + t] = 0.f;         // zeroed before k1's atomics (stream order)
  for (int n = t; n < NPTS; n += 256) labS[n] = labels[b * NPTS + n];
  __syncthreads();
  float accf = 0.f;
  int cnt = 0;
  for (int n = 0; n < NPTS; n += 4) {
    const int4 l4 = *(const int4*)&labS[n];
    if (l4.x == s) { cnt++; accf += features[(b * NPTS + n + 0) * DIM + t]; }
    if (l4.y == s) { cnt++; accf += features[(b * NPTS + n + 1) * DIM + t]; }
    if (l4.z == s) { cnt++; accf += features[(b * NPTS + n + 2) * DIM + t]; }
    if (l4.w == s) { cnt++; accf += features[(b * NPTS + n + 3) * DIM + t]; }
  }
  const float denom = fmaxf((float)cnt, 1.f);
  mfS[t] = accf / denom;
  __syncthreads();
  float hval = 0.f;
  if (t < HID) {
    float o = ag_b1[t];
    for (int k = 0; k < DIM; k += 4) {
      const f32x4 x = *(const f32x4*)&mfS[k];
      const f32x4 w = *(const f32x4*)&ag_w1[t * DIM + k];
      o += x[0] * w[0] + x[1] * w[1] + x[2] * w[2] + x[3] * w[3];
    }
    hval = o;
  }
  float sv = (t < HID) ? hval : 0.f;
  float qv = (t < HID) ? hval * hval : 0.f;
  #pragma unroll
  for (int off = 1; off < 64; off <<= 1) { sv += __shfl_xor(sv, off); qv += __shfl_xor(qv, off); }
  if (lane == 0 && wid < 2) { red[wid * 2] = sv; red[wid * 2 + 1] = qv; }
  __syncthreads();
  if (t < HID) {
    const float s1 = red[0] + red[2], q1 = red[1] + red[3];
    const float mean = s1 * (1.f / 128.f);
    const float var = fmaxf(q1 * (1.f / 128.f) - mean * mean, 0.f);
    const float rs = rsqrtf(var + LN_EPS);
    h1S[t] = fmaxf((hval - mean) * rs * ag_g1[t] + ag_be1[t], 0.f);
  }
  __syncthreads();
  float o = ag_b2[t];
  for (int k = 0; k < HID; k += 4) {
    const f32x4 x = *(const f32x4*)&h1S[k];
    const f32x4 w = *(const f32x4*)&ag_w2[t * HID + k];
    o += x[0] * w[0] + x[1] * w[1] + x[2] * w[2] + x[3] * w[3];
  }
  float sv2 = o, qv2 = o * o;
  #pragma unroll
  for (int off = 1; off < 64; off <<= 1) { sv2 += __shfl_xor(sv2, off); qv2 += __shfl_xor(qv2, off); }
  if (lane == 0) { red[wid * 2] = sv2; red[wid * 2 + 1] = qv2; }
  __syncthreads();
  const float sa = red[0] + red[2] + red[4] + red[6];
  const float qa = red[1] + red[3] + red[5] + red[7];
  const float mean = sa * (1.f / 256.f);
  const float var = fmaxf(qa * (1.f / 256.f) - mean * mean, 0.f);
  const float rs = rsqrtf(var + LN_EPS);
  comb[(b * NSEG + s) * DIM + t] = (o - mean) * rs * ag_g2[t] + ag_be2[t];  // agg only (no mg)
  if (t == 0) cntf[b * NSEG + s] = (float)cnt;
}

// ---------------- K1 v6 core (unchanged) + atomic mgsum accumulation ---------------------
__global__ __launch_bounds__(256, 4) void k1_geo(
    fpc coords, const int* __restrict__ labels,
    fpc g1, fpc be1, fpc w1, fpc b1,
    fpc w2, fpc b2, fpc g2, fpc be2,
    const unsigned short* __restrict__ gmw, fpc uw, fpc tvw, fpc scw, fpc qfw,
    float* __restrict__ geo_ctx, float* __restrict__ mgsum)
{
  const int t = threadIdx.x;
  const int lane = t & 63;
  const int wid = t >> 6;
  const int bi = blockIdx.x;           // b*512 + i
  const int b = bi >> 9;

  __shared__ __align__(16) float xs[NPTS][8];
  __shared__ __align__(16) float st[NPTS][2];
  __shared__ __align__(16) float qf[128];
  __shared__ __align__(16) unsigned short h1s[32][136];
  __shared__ __align__(16) float red2[32][12];
  __shared__ __align__(16) float haS[128];
  __shared__ float srsS, srmS;

  if (t < 128) qf[t] = qfw[t];

  float w1r[2][7], b1r[2], g1r[2], be1r[2];
  #pragma unroll
  for (int r = 0; r < 2; ++r) {
    const int hh = lane * 2 + r;
    w1r[r][0] = w1[hh * 9 + 0]; w1r[r][1] = w1[hh * 9 + 1];
    w1r[r][2] = w1[hh * 9 + 2]; w1r[r][3] = w1[hh * 9 + 3];
    w1r[r][4] = w1[hh * 9 + 6]; w1r[r][5] = w1[hh * 9 + 7];
    w1r[r][6] = w1[hh * 9 + 8];
    b1r[r] = b1[hh]; g1r[r] = g1[hh]; be1r[r] = be1[hh];
  }
  const int n16 = lane & 15;
  const int q16 = lane >> 4;
  const int colc0 = wid * 32 + n16;
  s16x8 gfrag[2][4];
  float u_c[2], tv_c[2];
  #pragma unroll
  for (int dt = 0; dt < 2; ++dt) {
    const int c = colc0 + dt * 16;
    u_c[dt] = uw[c];
    tv_c[dt] = 2.f * tvw[c];
    #pragma unroll
    for (int kt = 0; kt < 4; ++kt)
      gfrag[dt][kt] = *(const s16x8*)&gmw[c * HID + kt * 32 + q16 * 8];
  }
  const float sb = scw[0], sb2 = scw[1];
  const float cix = coords[bi * 3 + 0];
  const float ciy = coords[bi * 3 + 1];
  const float ciz = coords[bi * 3 + 2];
  __syncthreads();

  #pragma unroll
  for (int jj = 0; jj < 2; ++jj) {
    const int j = t + jj * 256;
    const float cjx = coords[(b * NPTS + j) * 3 + 0];
    const float cjy = coords[(b * NPTS + j) * 3 + 1];
    const float cjz = coords[(b * NPTS + j) * 3 + 2];
    const float rx = cix - cjx, ry = ciy - cjy, rz = ciz - cjz;
    const float dist = sqrtf(rx * rx + ry * ry + rz * rz);
    const float inv = 1.f / fmaxf(dist, 1e-12f);
    const float r0 = rx * inv, r1 = ry * inv, r2 = rz * inv;
    const float x0 = dist, x1 = r0, x2 = r1, x3 = r2;
    const float x6 = r1 * r2, x7 = r0 * r1, x8 = r0 * r2;
    float S1 = qf[126] + qf[108] * x0 + qf[109] * x1 + qf[110] * x2 + qf[111] * x3
             + qf[114] * x6 + qf[115] * x7 + qf[116] * x8;
    float tx = qf[117] * x0 + qf[118] * x1 + qf[119] * x2 + qf[120] * x3
             + qf[123] * x6 + qf[124] * x7 + qf[125] * x8;
    const float xv[9] = {x0, x1, x2, x3, 0.f, 0.f, x6, x7, x8};
    float quad = 0.f;
    #pragma unroll
    for (int a = 0; a < 9; ++a) {
      if (a == 4 || a == 5) continue;
      const f32x4 q0 = *(const f32x4*)&qf[a * 12];
      const f32x4 q1 = *(const f32x4*)&qf[a * 12 + 4];
      const f32x4 q2 = *(const f32x4*)&qf[a * 12 + 8];
      const float ya = q0[0] * x0 + q0[1] * x1 + q0[2] * x2 + q0[3] * x3
                     + q1[2] * x6 + q1[3] * x7 + q2[0] * x8;
      quad += ya * xv[a];
    }
    const float S2 = quad + 2.f * tx + qf[127];
    const float mean = S1 * (1.f / 128.f);
    const float var = fmaxf(S2 * (1.f / 128.f) - mean * mean, 0.f);
    st[j][0] = mean;
    st[j][1] = rsqrtf(var + LN_EPS);
    f32x4 X0; X0[0] = x0; X0[1] = x1; X0[2] = x2; X0[3] = x3;
    f32x4 X1; X1[0] = x6; X1[1] = x7; X1[2] = x8; X1[3] = 0.f;
    *(f32x4*)&xs[j][0] = X0;
    *(f32x4*)&xs[j][4] = X1;
  }
  __syncthreads();

  float haL[2] = {0.f, 0.f};
  float srs = 0.f, srm = 0.f;
  const bool own = (wid == 0) && (n16 == 0);

  for (int jb = 0; jb < NPTS; jb += 32) {
    #pragma unroll
    for (int sr = 0; sr < 8; ++sr) {
      const int m = sr * 4 + wid;
      const int j = jb + m;
      const f32x4 X0 = *(const f32x4*)&xs[j][0];
      const f32x4 X1 = *(const f32x4*)&xs[j][4];
      const float2 ms = *(const float2*)&st[j][0];
      unsigned int pk = 0;
      #pragma unroll
      for (int r = 0; r < 2; ++r) {
        const float a = b1r[r]
          + X0[0] * w1r[r][0] + X0[1] * w1r[r][1] + X0[2] * w1r[r][2] + X0[3] * w1r[r][3]
          + X1[0] * w1r[r][4] + X1[1] * w1r[r][5] + X1[2] * w1r[r][6];
        const float e = (a - ms.x) * ms.y * g1r[r] + be1r[r];
        pk |= ((unsigned int)f2bf(fmaxf(e, 0.f))) << (16 * r);
      }
      *(unsigned int*)&h1s[m][lane * 2] = pk;
    }
    __syncthreads();
    f32x4 acc2[2][2];
    #pragma unroll
    for (int mt = 0; mt < 2; ++mt)
      #pragma unroll
      for (int dt = 0; dt < 2; ++dt) {
        f32x4 z; z[0] = tv_c[dt]; z[1] = tv_c[dt]; z[2] = tv_c[dt]; z[3] = tv_c[dt];
        acc2[mt][dt] = z;
      }
    #pragma unroll
    for (int mt = 0; mt < 2; ++mt)
      #pragma unroll
      for (int kt = 0; kt < 4; ++kt) {
        const s16x8 af = *(const s16x8*)&h1s[mt * 16 + n16][kt * 32 + q16 * 8];
        #pragma unroll
        for (int dt = 0; dt < 2; ++dt)
          acc2[mt][dt] = __builtin_amdgcn_mfma_f32_16x16x32_bf16(af, gfrag[dt][kt], acc2[mt][dt], 0, 0, 0);
      }
    float h1v[2][2][4];
    #pragma unroll
    for (int mt = 0; mt < 2; ++mt)
      #pragma unroll
      for (int dt = 0; dt < 2; ++dt)
        #pragma unroll
        for (int r = 0; r < 4; ++r) {
          const unsigned short hv = h1s[mt * 16 + q16 * 4 + r][colc0 + dt * 16];
          h1v[mt][dt][r] = __builtin_bit_cast(float, ((unsigned int)hv) << 16);
        }
    #pragma unroll
    for (int mt = 0; mt < 2; ++mt) {
      float sR[4], qR[4];
      #pragma unroll
      for (int r = 0; r < 4; ++r) {
        sR[r] = u_c[0] * h1v[mt][0][r] + u_c[1] * h1v[mt][1][r];
        qR[r] = acc2[mt][0][r] * h1v[mt][0][r] + acc2[mt][1][r] * h1v[mt][1][r];
      }
      #pragma unroll
      for (int off = 1; off < 16; off <<= 1)
        #pragma unroll
        for (int r = 0; r < 4; ++r) {
          sR[r] += __shfl_xor(sR[r], off);
          qR[r] += __shfl_xor(qR[r], off);
        }
      if (n16 == 0)
        #pragma unroll
        for (int r = 0; r < 4; ++r) {
          red2[mt * 16 + q16 * 4 + r][wid * 2 + 0] = sR[r];
          red2[mt * 16 + q16 * 4 + r][wid * 2 + 1] = qR[r];
        }
    }
    __syncthreads();
    #pragma unroll
    for (int mt = 0; mt < 2; ++mt)
      #pragma unroll
      for (int r = 0; r < 4; ++r) {
        const int row = mt * 16 + q16 * 4 + r;
        const f32x4 p0 = *(const f32x4*)&red2[row][0];
        const f32x4 p1 = *(const f32x4*)&red2[row][4];
        const float s = p0[0] + p0[2] + p1[0] + p1[2];
        const float q = p0[1] + p0[3] + p1[1] + p1[3];
        const float mean = (s + sb) * (1.f / 256.f);
        const float var = fmaxf((q + sb2) * (1.f / 256.f) - mean * mean, 0.f);
        const float rs = rsqrtf(var + LN_EPS);
        haL[0] += rs * h1v[mt][0][r];
        haL[1] += rs * h1v[mt][1][r];
        if (own) { srs += rs; srm += rs * mean; }
      }
  }

  haL[0] += __shfl_xor(haL[0], 16); haL[0] += __shfl_xor(haL[0], 32);
  haL[1] += __shfl_xor(haL[1], 16); haL[1] += __shfl_xor(haL[1], 32);
  float sa = srs, sm = srm;
  sa += __shfl_xor(sa, 16); sa += __shfl_xor(sa, 32);
  sm += __shfl_xor(sm, 16); sm += __shfl_xor(sm, 32);
  if (t == 0) { srsS = sa; srmS = sm; }
  if (lane < 16) { haS[colc0] = haL[0]; haS[colc0 + 16] = haL[1]; }
  __syncthreads();
  const float srsT = srsS, srmT = srmS;
  float dot = 0.f;
  for (int k = 0; k < HID; k += 4) {
    const f32x4 w = *(const f32x4*)&w2[t * HID + k];
    const f32x4 h = *(const f32x4*)&haS[k];
    dot += w[0] * h[0] + w[1] * h[1] + w[2] * h[2] + w[3] * h[3];
  }
  const float gv = (dot + b2[t] * srsT - srmT) * (1.f / 512.f) * g2[t] + be2[t];
  geo_ctx[bi * DIM + t] = gv;
  // segment-mean accumulation for comb (replaces k2's geo pass; mgsum zeroed in k02)
  const int l = labels[bi];
  atomicAdd(&mgsum[(b * NSEG + l) * DIM + t], gv);
}

// ---------------- K4: QKV proj; Q-path composes comb=agg+mg/cnt, writes out base ---------
__global__ __launch_bounds__(256) void k4_qkv(
    fpc features, const int* __restrict__ labels,
    const float* __restrict__ comb, const float* __restrict__ cntf,
    const float* __restrict__ mgsum, const float* __restrict__ geo_ctx,
    fpc wq, fpc bq, fpc wk, fpc bk, fpc wv, fpc bv, fpc bo,
    float* __restrict__ Q, float* __restrict__ Ko, float* __restrict__ V,
    float* __restrict__ enh, float* __restrict__ outb)
{
  const int blk = blockIdx.x;
  const int proj = blk >> 7;           // 3 x 128
  const int rem = blk & 127;
  const int b = rem >> 6;
  const int nt = rem & 63;
  const int n0 = b * NPTS + nt * 8;
  fpc W = (proj == 0) ? wq : (proj == 1 ? wk : wv);
  fpc bias = (proj == 0) ? bq : (proj == 1 ? bk : bv);
  float* out = (proj == 0) ? Q : (proj == 1 ? Ko : V);
  __shared__ __align__(16) float Xs[8][256];
  const int t = threadIdx.x;
  for (int idx = t * 4; idx < 8 * 256; idx += 1024) {
    const int r = idx >> 8, c = idx & 255;
    const int row = n0 + r;
    f32x4 v;
    if (proj == 0) {
      const int l = labels[row];
      const float cn = cntf[b * NSEG + l];
      const f32x4 f = *(const f32x4*)&features[row * DIM + c];
      if (cn >= 2.f) {
        const f32x4 ag = *(const f32x4*)&comb[(b * NSEG + l) * DIM + c];
        const f32x4 mg = *(const f32x4*)&mgsum[(b * NSEG + l) * DIM + c];
        const float rcn = 1.f / cn;
        #pragma unroll
        for (int i = 0; i < 4; ++i) v[i] = 0.7f * f[i] + 0.3f * (ag[i] + mg[i] * rcn);
      } else {
        v = f;
      }
      *(f32x4*)&enh[row * DIM + c] = v;
      const f32x4 bo4 = *(const f32x4*)&bo[c];
      f32x4 ob;
      #pragma unroll
      for (int i = 0; i < 4; ++i) ob[i] = v[i] + 0.5f * bo4[i];
      *(f32x4*)&outb[row * DIM + c] = ob;    // base for k5's atomic wo-partials
    } else {
      v = *(const f32x4*)&geo_ctx[row * DIM + c];
    }
    *(f32x4*)&Xs[r][c] = v;
  }
  __syncthreads();
  const int r0 = (t >> 6) * 2;
  const int c0 = (t & 63) * 4;
  float acc[2][4] = {};
  for (int k = 0; k < DIM; k += 4) {
    f32x4 xq[2];
    xq[0] = *(const f32x4*)&Xs[r0][k];
    xq[1] = *(const f32x4*)&Xs[r0 + 1][k];
    f32x4 wf[4];
    #pragma unroll
    for (int c = 0; c < 4; ++c) wf[c] = *(const f32x4*)&W[(c0 + c) * DIM + k];
    #pragma unroll
    for (int r = 0; r < 2; ++r)
      #pragma unroll
      for (int c = 0; c < 4; ++c)
        acc[r][c] += xq[r][0] * wf[c][0] + xq[r][1] * wf[c][1]
                   + xq[r][2] * wf[c][2] + xq[r][3] * wf[c][3];
  }
  #pragma unroll
  for (int r = 0; r < 2; ++r) {
    f32x4 o;
    #pragma unroll
    for (int c = 0; c < 4; ++c) o[c] = acc[r][c] + bias[c0 + c];
    *(f32x4*)&out[(n0 + r0 + r) * DIM + c0] = o;
  }
}

// ---------------- K5: attention + per-head wo partial, atomicAdd into out ----------------
// out = enh + 0.5*(O@wo^T + bo) = base(k4) + sum_h 0.5*(O_h @ wo_h^T)  — k6 eliminated.
__global__ void k5_attn(const float* __restrict__ Q, const float* __restrict__ Kv,
                        const float* __restrict__ V, fpc wo, float* __restrict__ out)
{
  const int blk = blockIdx.x;
  const int qt = blk & 31;
  const int h = (blk >> 5) & 7;
  const int b = blk >> 8;
  const int t = threadIdx.x;
  __shared__ __align__(16) float Sx[16][516];
  __shared__ __align__(16) float rinv[16];
  __shared__ __align__(16) float Oc[16][34];
  {
    const int r = t & 15, kc = t >> 4;
    const int qrow = b * NPTS + qt * 16 + r;
    f32x4 qv[8];
    #pragma unroll
    for (int i = 0; i < 8; ++i) qv[i] = *(const f32x4*)&Q[qrow * DIM + h * 32 + i * 4];
    for (int kk = 0; kk < 32; ++kk) {
      const int krow = b * NPTS + kc * 32 + kk;
      const f32x4* kp = (const f32x4*)&Kv[krow * DIM + h * 32];
      float sd = 0.f;
      #pragma unroll
      for (int i = 0; i < 8; ++i) {
        const f32x4 kvv = kp[i];
        sd += qv[i][0] * kvv[0] + qv[i][1] * kvv[1] + qv[i][2] * kvv[2] + qv[i][3] * kvv[3];
      }
      Sx[r][kc * 32 + kk] = sd * 0.1767766952966369f;   // 1/sqrt(32)
    }
  }
  __syncthreads();
  {
    const int r2 = t >> 4, cl = t & 15;
    float mx = -3.4e38f;
    for (int i = 0; i < 32; ++i) mx = fmaxf(mx, Sx[r2][cl + 16 * i]);
    #pragma unroll
    for (int off = 1; off < 16; off <<= 1) mx = fmaxf(mx, __shfl_xor(mx, off));
    float sm = 0.f;
    for (int i = 0; i < 32; ++i) {
      const float e = __expf(Sx[r2][cl + 16 * i] - mx);
      Sx[r2][cl + 16 * i] = e;
      sm += e;
    }
    #pragma unroll
    for (int off = 1; off < 16; off <<= 1) sm += __shfl_xor(sm, off);
    if (cl == 0) rinv[r2] = 1.f / sm;
  }
  __syncthreads();
  {
    const int r3 = t >> 4;
    const int e0 = (t & 15) * 2;
    float o0 = 0.f, o1 = 0.f;
    for (int k = 0; k < NPTS; ++k) {
      const float p = Sx[r3][k];
      const float2 vv = *(const float2*)&V[(b * NPTS + k) * DIM + h * 32 + e0];
      o0 += p * vv.x; o1 += p * vv.y;
    }
    const float ri = rinv[r3];
    Oc[r3][e0] = o0 * ri;
    Oc[r3][e0 + 1] = o1 * ri;
  }
  __syncthreads();
  {
    // wo partial: thread (r = t&15, cg = t>>4) does row r, cols cg*16..+15
    const int r = t & 15;
    const int c0p = (t >> 4) * 16;
    const int row = b * NPTS + qt * 16 + r;
    float oc[32];
    #pragma unroll
    for (int j = 0; j < 32; ++j) oc[j] = Oc[r][j];
    #pragma unroll
    for (int c = 0; c < 16; ++c) {
      fpc wr = &wo[(c0p + c) * DIM + h * 32];
      float d = 0.f;
      #pragma unroll
      for (int j = 0; j < 32; j += 4) {
        const f32x4 w = *(const f32x4*)&wr[j];
        d += w[0] * oc[j] + w[1] * oc[j + 1] + w[2] * oc[j + 2] + w[3] * oc[j + 3];
      }
      atomicAdd(&out[row * DIM + c0p + c], 0.5f * d);
    }
  }
}

extern "C" void kernel_launch(void* const* d_in, const int* in_sizes, int n_in,
                              void* d_out, int out_size, void* d_ws, size_t ws_size,
                              hipStream_t stream)
{
  fpc coords  = (fpc)d_in[0];
  fpc features= (fpc)d_in[1];
  const int* labels = (const int*)d_in[2];
  fpc ge_w1 = (fpc)d_in[3],  ge_b1 = (fpc)d_in[4],  ge_g1 = (fpc)d_in[5],  ge_be1 = (fpc)d_in[6];
  fpc ge_w2 = (fpc)d_in[7],  ge_b2 = (fpc)d_in[8],  ge_g2 = (fpc)d_in[9],  ge_be2 = (fpc)d_in[10];
  fpc ag_w1 = (fpc)d_in[11], ag_b1 = (fpc)d_in[12], ag_g1 = (fpc)d_in[13], ag_be1 = (fpc)d_in[14];
  fpc ag_w2 = (fpc)d_in[15], ag_b2 = (fpc)d_in[16], ag_g2 = (fpc)d_in[17], ag_be2 = (fpc)d_in[18];
  fpc wq = (fpc)d_in[19], bq = (fpc)d_in[20];
  fpc wk = (fpc)d_in[21], bk = (fpc)d_in[22];
  fpc wv = (fpc)d_in[23], bv = (fpc)d_in[24];
  fpc wo = (fpc)d_in[25], bo = (fpc)d_in[26];

  float* ws = (float*)d_ws;
  float* geo_ctx = ws;                    // 262144
  float* comb    = geo_ctx + 262144;      // 32768
  float* cntf    = comb + 32768;          // 128
  float* enh     = cntf + 128;            // 262144
  float* Qb      = enh + 262144;          // 262144
  float* Kb      = Qb + 262144;           // 262144
  float* Vb      = Kb + 262144;           // 262144
  float* mgsum   = Vb + 262144;           // 32768
  float* gmwF    = mgsum + 32768;         // 8192 floats (128x128 bf16)
  float* uw      = gmwF + 8192;           // 128
  float* tvw     = uw + 128;              // 128
  float* scw     = tvw + 128;             // 8
  float* qfw     = scw + 8;               // 128

  k02_prep_agg<<<258, 256, 0, stream>>>(ge_w1, ge_b1, ge_w2, ge_b2,
                                        features, labels,
                                        ag_w1, ag_b1, ag_g1, ag_be1,
                                        ag_w2, ag_b2, ag_g2, ag_be2,
                                        (unsigned short*)gmwF, uw, tvw, scw, qfw,
                                        comb, cntf, mgsum);
  k1_geo<<<1024, 256, 0, stream>>>(coords, labels, ge_g1, ge_be1, ge_w1, ge_b1,
                                   ge_w2, ge_b2, ge_g2, ge_be2,
                                   (const unsigned short*)gmwF, uw, tvw, scw, qfw,
                                   geo_ctx, mgsum);
  k4_qkv<<<384, 256, 0, stream>>>(features, labels, comb, cntf, mgsum, geo_ctx,
                                  wq, bq, wk, bk, wv, bv, bo,
                                  Qb, Kb, Vb, enh, (float*)d_out);
  k5_attn<<<512, 256, 0, stream>>>(Qb, Kb, Vb, wo, (float*)d_out);
}